// Round 2
// baseline (14111.208 us; speedup 1.0000x reference)
//
#include <hip/hip_runtime.h>
#include <hip/hip_bf16.h>

// Problem constants: N=20000 nodes, E=100000 edges, L=4 steps, D=64, H=8, HID=512.
#define N_NODES 20000
#define E_EDGES 100000
#define L_SEQ   4
#define D_FEAT  64
#define H_HEADS 8
#define HID     512

// ---------- math helpers ----------
__device__ __forceinline__ float sigmoidf_(float x) {
    return 1.0f / (1.0f + __expf(-x));
}
__device__ __forceinline__ float tanhf_(float x) {
    x = fminf(15.f, fmaxf(-15.f, x));
    float e = __expf(2.f * x);
    return (e - 1.f) / (e + 1.f);
}
// order-preserving float -> uint for atomicMax-based segment max (0 == "empty")
__device__ __forceinline__ unsigned fkey(float f) {
    unsigned u = __float_as_uint(f);
    return (u & 0x80000000u) ? ~u : (u | 0x80000000u);
}
__device__ __forceinline__ float fdecode(unsigned k) {
    if (k == 0u) return 0.0f;  // empty segment: reference maps non-finite max -> 0
    unsigned u = (k & 0x80000000u) ? (k ^ 0x80000000u) : ~k;
    return __uint_as_float(u);
}

// element-type conversion (eft may be fp32 or bf16 depending on ws_size)
template <typename T> __device__ __forceinline__ T     to_et(float v);
template <> __device__ __forceinline__ float           to_et<float>(float v) { return v; }
template <> __device__ __forceinline__ __hip_bfloat16  to_et<__hip_bfloat16>(float v) { return __float2bfloat16(v); }
template <typename T> __device__ __forceinline__ float from_et(T v);
template <> __device__ __forceinline__ float from_et<float>(float v) { return v; }
template <> __device__ __forceinline__ float from_et<__hip_bfloat16>(__hip_bfloat16 v) { return __bfloat162float(v); }

// ---------- fused LSTM step over an edge chunk ----------
// gates = [x_t | h_prev] @ [W_ih|W_hh]^T + b, then cell update.
// Tile: 32 edges x 32 hidden (x4 gates), K chunked by 64. 256 thr, 4x1x4 acc/thread.
// h_prev/c chunk-local fp32; h_next is ET (float for t<3, eft dtype at t=3).
template <typename ET>
__global__ __launch_bounds__(256) void lstm_step(
    const float* __restrict__ features,   // N x 64
    const int*   __restrict__ mp,         // chunk-offset: cnt x 4
    const float* __restrict__ W_ih,       // 2048 x 64
    const float* __restrict__ W_hh,       // 2048 x 512
    const float* __restrict__ b_ih,
    const float* __restrict__ b_hh,
    const float* __restrict__ h_prev,     // cnt x 512 (ignored when first=1)
    ET*          __restrict__ h_next,     // cnt x 512
    float*       __restrict__ c_state,    // cnt x 512 (in-place; not read when first=1)
    int t, int first)
{
    __shared__ float Asub[32][68];
    __shared__ float Wsub[128][68];

    const int tid = threadIdx.x;
    const int tx  = tid & 31;
    const int ty  = tid >> 5;
    const int e0  = blockIdx.x * 32;   // chunk-local
    const int n0  = blockIdx.y * 32;

    float acc[4][4];
#pragma unroll
    for (int r = 0; r < 4; ++r)
#pragma unroll
        for (int q = 0; q < 4; ++q) acc[r][q] = 0.f;

    const int nchunks = first ? 1 : 9;

    for (int kc = 0; kc < nchunks; ++kc) {
#pragma unroll
        for (int i = 0; i < 2; ++i) {
            int s = tid + 256 * i;
            int m = s >> 4, kv = s & 15;
            float4 v;
            if (kc == 0) {
                int row = mp[(e0 + m) * L_SEQ + t];
                v = *(const float4*)&features[row * D_FEAT + kv * 4];
            } else {
                v = *(const float4*)&h_prev[(e0 + m) * HID + (kc - 1) * 64 + kv * 4];
            }
            *(float4*)&Asub[m][kv * 4] = v;
        }
#pragma unroll
        for (int i = 0; i < 8; ++i) {
            int s = tid + 256 * i;
            int row_l = s >> 4, kv = s & 15;
            int q = row_l >> 5, n_l = row_l & 31;
            int grow = q * HID + n0 + n_l;
            float4 v;
            if (kc == 0) v = *(const float4*)&W_ih[grow * D_FEAT + kv * 4];
            else         v = *(const float4*)&W_hh[grow * HID + (kc - 1) * 64 + kv * 4];
            *(float4*)&Wsub[row_l][kv * 4] = v;
        }
        __syncthreads();

#pragma unroll
        for (int kk = 0; kk < 64; kk += 4) {
            float4 av[4], wv[4];
            av[0] = *(const float4*)&Asub[ty][kk];
            av[1] = *(const float4*)&Asub[ty + 8][kk];
            av[2] = *(const float4*)&Asub[ty + 16][kk];
            av[3] = *(const float4*)&Asub[ty + 24][kk];
            wv[0] = *(const float4*)&Wsub[tx][kk];
            wv[1] = *(const float4*)&Wsub[32 + tx][kk];
            wv[2] = *(const float4*)&Wsub[64 + tx][kk];
            wv[3] = *(const float4*)&Wsub[96 + tx][kk];
#pragma unroll
            for (int r = 0; r < 4; ++r)
#pragma unroll
                for (int q = 0; q < 4; ++q) {
                    acc[r][q] = fmaf(av[r].x, wv[q].x, acc[r][q]);
                    acc[r][q] = fmaf(av[r].y, wv[q].y, acc[r][q]);
                    acc[r][q] = fmaf(av[r].z, wv[q].z, acc[r][q]);
                    acc[r][q] = fmaf(av[r].w, wv[q].w, acc[r][q]);
                }
        }
        __syncthreads();
    }

    const int n_g = n0 + tx;
    float bsum[4];
#pragma unroll
    for (int q = 0; q < 4; ++q)
        bsum[q] = b_ih[q * HID + n_g] + b_hh[q * HID + n_g];

#pragma unroll
    for (int r = 0; r < 4; ++r) {
        int e = e0 + ty + 8 * r;
        float gi = acc[r][0] + bsum[0];
        float gf = acc[r][1] + bsum[1];
        float gg = acc[r][2] + bsum[2];
        float go = acc[r][3] + bsum[3];
        float c_old = first ? 0.f : c_state[e * HID + n_g];
        float cn = sigmoidf_(gf) * c_old + sigmoidf_(gi) * tanhf_(gg);
        c_state[e * HID + n_g] = cn;
        h_next[e * HID + n_g] = to_et<ET>(sigmoidf_(go) * tanhf_(cn));
    }
}

// ---------- attention logits + segment max (one 64-lane wave per edge) ----------
template <typename ET>
__global__ __launch_bounds__(256) void attn_logits(
    const float* __restrict__ features,
    const int*   __restrict__ mp,
    const ET*    __restrict__ hfin,      // E x 512 = eft (E,H,D)
    const float* __restrict__ attn1_w,   // H x 64
    const float* __restrict__ attn2,     // H x 64
    const int*   __restrict__ dst,
    float*       __restrict__ a_out,     // E x H
    unsigned*    __restrict__ amax_key)  // N x H
{
    const int e    = blockIdx.x * 4 + (threadIdx.x >> 6);
    const int lane = threadIdx.x & 63;
    const int ctr  = mp[e * L_SEQ + (L_SEQ - 1)];
    const float cd = features[ctr * D_FEAT + lane];
    const int dn   = dst[e];
#pragma unroll
    for (int h = 0; h < H_HEADS; ++h) {
        float v = cd * attn1_w[h * D_FEAT + lane]
                + from_et<ET>(hfin[(size_t)e * HID + h * D_FEAT + lane]) * attn2[h * D_FEAT + lane];
#pragma unroll
        for (int off = 32; off; off >>= 1) v += __shfl_xor(v, off, 64);
        if (lane == 0) {
            float lv = v > 0.f ? v : 0.01f * v;   // leaky_relu
            a_out[e * H_HEADS + h] = lv;
            atomicMax(&amax_key[dn * H_HEADS + h], fkey(lv));
        }
    }
}

// ---------- ex = exp(a - amax[dst]); denom = segment_sum(ex) ----------
__global__ __launch_bounds__(256) void exp_denom(
    const int*      __restrict__ dst,
    float*          __restrict__ a_out,
    const unsigned* __restrict__ amax_key,
    float*          __restrict__ denom)
{
    int i = blockIdx.x * 256 + threadIdx.x;
    if (i >= E_EDGES * H_HEADS) return;
    int e = i >> 3, h = i & 7;
    int dn = dst[e];
    float am = fdecode(amax_key[dn * H_HEADS + h]);
    float ex = __expf(a_out[i] - am);
    a_out[i] = ex;
    atomicAdd(&denom[dn * H_HEADS + h], ex);
}

// ---------- out[dst] += eft * ex/denom[dst] ----------
template <typename ET>
__global__ __launch_bounds__(256) void scatter_out(
    const int*   __restrict__ dst,
    const float* __restrict__ a_out,
    const float* __restrict__ denom,
    const ET*    __restrict__ hfin,
    float*       __restrict__ out)
{
    const int e  = blockIdx.x;
    const int dn = dst[e];
    for (int j = threadIdx.x; j < HID; j += 256) {
        int h = j >> 6;
        float w = a_out[e * H_HEADS + h] / denom[dn * H_HEADS + h];
        atomicAdd(&out[(size_t)dn * HID + j], from_et<ET>(hfin[(size_t)e * HID + j]) * w);
    }
}

extern "C" void kernel_launch(void* const* d_in, const int* in_sizes, int n_in,
                              void* d_out, int out_size, void* d_ws, size_t ws_size,
                              hipStream_t stream) {
    const float* features = (const float*)d_in[0];
    // d_in[1] = type_mask: unused by reference
    const int*   mp       = (const int*)d_in[2];
    const int*   dst      = (const int*)d_in[3];
    const float* W_ih     = (const float*)d_in[4];
    const float* W_hh     = (const float*)d_in[5];
    const float* b_ih     = (const float*)d_in[6];
    const float* b_hh     = (const float*)d_in[7];
    const float* attn1_w  = (const float*)d_in[8];
    const float* attn2    = (const float*)d_in[9];
    float* out = (float*)d_out;

    // ---- adaptive workspace layout (ws_size is constant across calls -> same path every call) ----
    char* ws = (char*)d_ws;
    size_t off = 0;
    float*    a_scr    = (float*)(ws + off); off += (size_t)E_EDGES * H_HEADS * sizeof(float);   // 3.2 MB
    float*    denom    = (float*)(ws + off); off += (size_t)N_NODES * H_HEADS * sizeof(float);   // 0.64 MB
    unsigned* amax_key = (unsigned*)(ws + off); off += (size_t)N_NODES * H_HEADS * sizeof(unsigned);
    off = (off + 255) & ~(size_t)255;

    const size_t eft_f32_b  = (size_t)E_EDGES * HID * sizeof(float);            // 204.8 MB
    const size_t eft_bf16_b = (size_t)E_EDGES * HID * sizeof(__hip_bfloat16);   // 102.4 MB
    const size_t per_edge_3buf = 3 * (size_t)HID * sizeof(float);               // hA+hB+c per edge

    // prefer fp32 eft when it leaves room for decent chunks (cs >= 6400)
    bool eft_fp32 = (ws_size >= off + eft_f32_b + 6400 * per_edge_3buf + 4096);
    size_t eft_b = eft_fp32 ? eft_f32_b : eft_bf16_b;
    void* eft = (void*)(ws + off); off += eft_b;
    off = (off + 255) & ~(size_t)255;

    // chunk size: largest multiple of 32 whose 3 fp32 h/c buffers fit in the remainder
    size_t avail = (ws_size > off) ? (ws_size - off) : 0;
    long long cs_ll = (long long)(avail / per_edge_3buf) & ~31LL;
    int cs = (int)(cs_ll < 32 ? 32 : (cs_ll > E_EDGES ? E_EDGES : cs_ll));

    float* hA = (float*)(ws + off);
    float* hB = hA + (size_t)cs * HID;
    float* cS = hB + (size_t)cs * HID;

    hipMemsetAsync(d_out, 0, (size_t)out_size * sizeof(float), stream);
    hipMemsetAsync(denom, 0, (size_t)N_NODES * H_HEADS * sizeof(float), stream);
    hipMemsetAsync(amax_key, 0, (size_t)N_NODES * H_HEADS * sizeof(unsigned), stream);

    for (int e0 = 0; e0 < E_EDGES; e0 += cs) {
        int cnt = E_EDGES - e0 < cs ? E_EDGES - e0 : cs;   // always a multiple of 32
        dim3 g(cnt / 32, HID / 32);
        const int* mpc = mp + (size_t)e0 * L_SEQ;
        // t0 -> hA, t1: hA->hB, t2: hB->hA, t3: hA -> eft[e0..]
        lstm_step<float><<<g, 256, 0, stream>>>(features, mpc, W_ih, W_hh, b_ih, b_hh, hA, hA, cS, 0, 1);
        lstm_step<float><<<g, 256, 0, stream>>>(features, mpc, W_ih, W_hh, b_ih, b_hh, hA, hB, cS, 1, 0);
        lstm_step<float><<<g, 256, 0, stream>>>(features, mpc, W_ih, W_hh, b_ih, b_hh, hB, hA, cS, 2, 0);
        if (eft_fp32) {
            lstm_step<float><<<g, 256, 0, stream>>>(features, mpc, W_ih, W_hh, b_ih, b_hh,
                hA, (float*)eft + (size_t)e0 * HID, cS, 3, 0);
        } else {
            lstm_step<__hip_bfloat16><<<g, 256, 0, stream>>>(features, mpc, W_ih, W_hh, b_ih, b_hh,
                hA, (__hip_bfloat16*)eft + (size_t)e0 * HID, cS, 3, 0);
        }
    }

    if (eft_fp32) {
        attn_logits<float><<<E_EDGES / 4, 256, 0, stream>>>(features, mp, (const float*)eft, attn1_w, attn2, dst, a_scr, amax_key);
        exp_denom<<<(E_EDGES * H_HEADS + 255) / 256, 256, 0, stream>>>(dst, a_scr, amax_key, denom);
        scatter_out<float><<<E_EDGES, 256, 0, stream>>>(dst, a_scr, denom, (const float*)eft, out);
    } else {
        attn_logits<__hip_bfloat16><<<E_EDGES / 4, 256, 0, stream>>>(features, mp, (const __hip_bfloat16*)eft, attn1_w, attn2, dst, a_scr, amax_key);
        exp_denom<<<(E_EDGES * H_HEADS + 255) / 256, 256, 0, stream>>>(dst, a_scr, amax_key, denom);
        scatter_out<__hip_bfloat16><<<E_EDGES, 256, 0, stream>>>(dst, a_scr, denom, (const __hip_bfloat16*)eft, out);
    }
}

// Round 3
// 1738.518 us; speedup vs baseline: 8.1168x; 8.1168x over previous
//
#include <hip/hip_runtime.h>
#include <hip/hip_bf16.h>
#include <stdint.h>

// N=20000 nodes, E=100000 edges, L=4 steps, D=64, H=8, HID=512, gates=2048.
#define N_NODES 20000
#define E_EDGES 100000
#define L_SEQ   4
#define D_FEAT  64
#define H_HEADS 8
#define HID     512

typedef __attribute__((ext_vector_type(8))) short short8;   // 8 bf16 = 4 VGPRs
typedef __attribute__((ext_vector_type(4))) float floatx4;  // MFMA C/D

// ---------- math helpers ----------
__device__ __forceinline__ float sigmoidf_(float x) { return 1.0f / (1.0f + __expf(-x)); }
__device__ __forceinline__ float tanhf_(float x) {
    x = fminf(15.f, fmaxf(-15.f, x));
    float e = __expf(2.f * x);
    return (e - 1.f) / (e + 1.f);
}
__device__ __forceinline__ unsigned fkey(float f) {
    unsigned u = __float_as_uint(f);
    return (u & 0x80000000u) ? ~u : (u | 0x80000000u);
}
__device__ __forceinline__ float fdecode(unsigned k) {
    if (k == 0u) return 0.0f;
    unsigned u = (k & 0x80000000u) ? (k ^ 0x80000000u) : ~k;
    return __uint_as_float(u);
}
__device__ __forceinline__ short f2bf(float x) {
    __hip_bfloat16 b = __float2bfloat16(x);
    return *(short*)&b;
}

// async global->LDS, 16B per lane; lds base must be wave-uniform (lane i lands at base + i*16)
__device__ __forceinline__ void gload16(const void* g, const void* l) {
    __builtin_amdgcn_global_load_lds(
        (const __attribute__((address_space(1))) unsigned int*)(uintptr_t)g,
        (__attribute__((address_space(3))) unsigned int*)(unsigned int)(uintptr_t)l,
        16, 0, 0);
}

// ---------- one-time conversions ----------
__global__ __launch_bounds__(256) void feat2bf16(const float* __restrict__ f, short* __restrict__ fb) {
    int i = blockIdx.x * 256 + threadIdx.x;
    if (i < N_NODES * D_FEAT) fb[i] = f2bf(f[i]);
}

// Permute W rows so a 128-row B-tile = 32 hidden units x 4 gates, with wave n-frags = gates.
// permuted row rp: hblock=rp>>7, half=(rp>>6)&1, gate=(rp>>4)&3, j=rp&15
// original row ro = gate*512 + hblock*32 + half*16 + j
__global__ __launch_bounds__(128) void convert_weights(
    const float* __restrict__ W_ih, const float* __restrict__ W_hh,
    const float* __restrict__ b_ih, const float* __restrict__ b_hh,
    short* __restrict__ Wb_ih, short* __restrict__ Wb_hh, float* __restrict__ bias)
{
    int rp = blockIdx.x;
    int hblock = rp >> 7, rem = rp & 127;
    int half = (rem >> 6) & 1, gate = (rem >> 4) & 3, j = rem & 15;
    int ro = gate * HID + hblock * 32 + half * 16 + j;
    for (int k = threadIdx.x; k < D_FEAT; k += 128)
        Wb_ih[rp * D_FEAT + k] = f2bf(W_ih[ro * D_FEAT + k]);
    for (int k = threadIdx.x; k < HID; k += 128)
        Wb_hh[rp * HID + k] = f2bf(W_hh[ro * HID + k]);
    if (threadIdx.x == 0) bias[ro] = b_ih[ro] + b_hh[ro];   // bias kept in ORIGINAL order
}

// ---------- MFMA LSTM step ----------
// C(cnt x 2048) = [x_t | h_prev](cnt x K) @ Wb^T, K = 64 (FIRST) or 576, then cell update.
// Block: 256 thr = 4 waves (2x2), tile 128 edges x 128 gate-cols (= 32 hidden x 4 gates).
// LDS kpart XOR swizzle: slot (m,p) holds global kpart p^(m&7)  -> ds_read_b128 2-way max.
template <int FIRST>
__global__ __launch_bounds__(256) void lstm_mfma(
    const short* __restrict__ feats_bf,   // N x 64 bf16
    const int*   __restrict__ mp,         // chunk: cnt x 4
    const short* __restrict__ Wb_ih,      // 2048 x 64 bf16 (permuted rows)
    const short* __restrict__ Wb_hh,      // 2048 x 512 bf16 (permuted rows)
    const float* __restrict__ bias,       // 2048 fp32 (original order)
    const short* __restrict__ h_prev,     // cnt x 512 bf16 (unused when FIRST)
    short*       __restrict__ h_next,     // cnt x 512 bf16
    float*       __restrict__ c_state,    // cnt x 512 fp32 (not read when FIRST)
    int t, int cnt)
{
    __shared__ __align__(16) short At[128 * 64];
    __shared__ __align__(16) short Bt[128 * 64];

    const int tid   = threadIdx.x;
    const int lane  = tid & 63;
    const int w     = tid >> 6;
    const int waveM = w & 1;
    const int waveN = w >> 1;
    const int quad  = lane >> 4;
    const int c16   = lane & 15;
    const int e0    = blockIdx.x * 128;
    const int bn    = blockIdx.y;          // 0..15
    const int hb    = bn * 32;             // hidden base for this block

    floatx4 acc[4][4];
#pragma unroll
    for (int a = 0; a < 4; ++a)
#pragma unroll
        for (int b = 0; b < 4; ++b) acc[a][b] = (floatx4){0.f, 0.f, 0.f, 0.f};

    const int nch = FIRST ? 1 : 9;
    for (int kc = 0; kc < nch; ++kc) {
        // ---- stage A and B tiles (128 rows x 64 bf16 each) via global_load_lds ----
#pragma unroll
        for (int i = 0; i < 4; ++i) {
            int sb = w * 256 + i * 64;         // wave-uniform slot base
            int s  = sb + lane;
            int m  = s >> 3, p = s & 7;
            int pg = p ^ (m & 7);              // swizzled global kpart
            // A row
            int e = e0 + m; if (e >= cnt) e = cnt - 1;
            const void* ga;
            if (kc == 0) {
                int row = mp[e * L_SEQ + t];
                ga = (const void*)(feats_bf + row * D_FEAT + pg * 8);
            } else {
                ga = (const void*)(h_prev + (size_t)e * HID + (kc - 1) * 64 + pg * 8);
            }
            gload16(ga, (const void*)&At[sb * 8]);
            // B row (permuted W)
            int r = bn * 128 + m;
            const void* gb = (kc == 0)
                ? (const void*)(Wb_ih + r * D_FEAT + pg * 8)
                : (const void*)(Wb_hh + (size_t)r * HID + (kc - 1) * 64 + pg * 8);
            gload16(gb, (const void*)&Bt[sb * 8]);
        }
        __syncthreads();

        // ---- 2 k-steps of 32, 16 MFMA each per wave ----
#pragma unroll
        for (int ks = 0; ks < 2; ++ks) {
            short8 af[4], bf[4];
#pragma unroll
            for (int mf = 0; mf < 4; ++mf) {
                int m  = waveM * 64 + mf * 16 + c16;
                int pw = ks * 4 + quad;
                af[mf] = *(const short8*)&At[m * 64 + ((pw ^ (m & 7)) * 8)];
            }
#pragma unroll
            for (int nf = 0; nf < 4; ++nf) {
                int n  = waveN * 64 + nf * 16 + c16;
                int pw = ks * 4 + quad;
                bf[nf] = *(const short8*)&Bt[n * 64 + ((pw ^ (n & 7)) * 8)];
            }
#pragma unroll
            for (int mf = 0; mf < 4; ++mf)
#pragma unroll
                for (int nf = 0; nf < 4; ++nf)
                    acc[mf][nf] = __builtin_amdgcn_mfma_f32_16x16x32_bf16(
                        af[mf], bf[nf], acc[mf][nf], 0, 0, 0);
        }
        __syncthreads();
    }

    // ---- epilogue: n-frag index IS the gate (0=i,1=f,2=g,3=o), all in-lane ----
    const int n = hb + waveN * 16 + c16;    // hidden unit
    const float bi = bias[n];
    const float bff = bias[HID + n];
    const float bg = bias[2 * HID + n];
    const float bo = bias[3 * HID + n];
#pragma unroll
    for (int mf = 0; mf < 4; ++mf) {
#pragma unroll
        for (int r = 0; r < 4; ++r) {
            int e = e0 + waveM * 64 + mf * 16 + quad * 4 + r;
            if (e < cnt) {
                float gi = acc[mf][0][r] + bi;
                float gf = acc[mf][1][r] + bff;
                float gg = acc[mf][2][r] + bg;
                float go = acc[mf][3][r] + bo;
                float c_old = FIRST ? 0.f : c_state[(size_t)e * HID + n];
                float cn = sigmoidf_(gf) * c_old + sigmoidf_(gi) * tanhf_(gg);
                c_state[(size_t)e * HID + n] = cn;
                h_next[(size_t)e * HID + n] = f2bf(sigmoidf_(go) * tanhf_(cn));
            }
        }
    }
}

// ---------- attention logits + segment max (one 64-lane wave per edge) ----------
__global__ __launch_bounds__(256) void attn_logits(
    const float* __restrict__ features,
    const int*   __restrict__ mp,
    const __hip_bfloat16* __restrict__ hfin,   // E x 512 (E,H,D)
    const float* __restrict__ attn1_w,
    const float* __restrict__ attn2,
    const int*   __restrict__ dst,
    float*       __restrict__ a_out,           // E x H
    unsigned*    __restrict__ amax_key)        // N x H
{
    const int e    = blockIdx.x * 4 + (threadIdx.x >> 6);
    const int lane = threadIdx.x & 63;
    const int ctr  = mp[e * L_SEQ + (L_SEQ - 1)];
    const float cd = features[ctr * D_FEAT + lane];
    const int dn   = dst[e];
#pragma unroll
    for (int h = 0; h < H_HEADS; ++h) {
        float v = cd * attn1_w[h * D_FEAT + lane]
                + __bfloat162float(hfin[(size_t)e * HID + h * D_FEAT + lane]) * attn2[h * D_FEAT + lane];
#pragma unroll
        for (int off = 32; off; off >>= 1) v += __shfl_xor(v, off, 64);
        if (lane == 0) {
            float lv = v > 0.f ? v : 0.01f * v;
            a_out[e * H_HEADS + h] = lv;
            atomicMax(&amax_key[dn * H_HEADS + h], fkey(lv));
        }
    }
}

__global__ __launch_bounds__(256) void exp_denom(
    const int*      __restrict__ dst,
    float*          __restrict__ a_out,
    const unsigned* __restrict__ amax_key,
    float*          __restrict__ denom)
{
    int i = blockIdx.x * 256 + threadIdx.x;
    if (i >= E_EDGES * H_HEADS) return;
    int e = i >> 3, h = i & 7;
    int dn = dst[e];
    float am = fdecode(amax_key[dn * H_HEADS + h]);
    float ex = __expf(a_out[i] - am);
    a_out[i] = ex;
    atomicAdd(&denom[dn * H_HEADS + h], ex);
}

__global__ __launch_bounds__(256) void scatter_out(
    const int*   __restrict__ dst,
    const float* __restrict__ a_out,
    const float* __restrict__ denom,
    const __hip_bfloat16* __restrict__ hfin,
    float*       __restrict__ out)
{
    const int e  = blockIdx.x;
    const int dn = dst[e];
    for (int j = threadIdx.x; j < HID; j += 256) {
        int h = j >> 6;
        float wgt = a_out[e * H_HEADS + h] / denom[dn * H_HEADS + h];
        atomicAdd(&out[(size_t)dn * HID + j], __bfloat162float(hfin[(size_t)e * HID + j]) * wgt);
    }
}

extern "C" void kernel_launch(void* const* d_in, const int* in_sizes, int n_in,
                              void* d_out, int out_size, void* d_ws, size_t ws_size,
                              hipStream_t stream) {
    const float* features = (const float*)d_in[0];
    // d_in[1] = type_mask: unused
    const int*   mp       = (const int*)d_in[2];
    const int*   dst      = (const int*)d_in[3];
    const float* W_ih     = (const float*)d_in[4];
    const float* W_hh     = (const float*)d_in[5];
    const float* b_ih     = (const float*)d_in[6];
    const float* b_hh     = (const float*)d_in[7];
    const float* attn1_w  = (const float*)d_in[8];
    const float* attn2    = (const float*)d_in[9];
    float* out = (float*)d_out;

    // ---- workspace layout (deterministic given ws_size -> graph-safe) ----
    char* ws = (char*)d_ws;
    size_t off = 0;
    float*    a_scr    = (float*)(ws + off); off += (size_t)E_EDGES * H_HEADS * sizeof(float);
    float*    denom    = (float*)(ws + off); off += (size_t)N_NODES * H_HEADS * sizeof(float);
    unsigned* amax_key = (unsigned*)(ws + off); off += (size_t)N_NODES * H_HEADS * sizeof(unsigned);
    short*    feats_bf = (short*)(ws + off); off += (size_t)N_NODES * D_FEAT * sizeof(short);
    short*    Wb_ih    = (short*)(ws + off); off += (size_t)4 * HID * D_FEAT * sizeof(short);
    short*    Wb_hh    = (short*)(ws + off); off += (size_t)4 * HID * HID * sizeof(short);
    float*    bias     = (float*)(ws + off); off += (size_t)4 * HID * sizeof(float);
    off = (off + 255) & ~(size_t)255;
    short*    eft      = (short*)(ws + off); off += (size_t)E_EDGES * HID * sizeof(short);  // 102.4 MB
    off = (off + 255) & ~(size_t)255;

    // chunk buffers: hA(bf16) + hB(bf16) + c(fp32) = 4 KB/edge
    const size_t per_edge = (size_t)HID * (2 + 2 + 4);
    size_t avail = (ws_size > off) ? (ws_size - off) : 0;
    long long cs_ll = ((long long)(avail / per_edge) / 128) * 128;
    int cs = (int)(cs_ll < 128 ? 128 : (cs_ll > E_EDGES ? E_EDGES : cs_ll));

    short* hA = (short*)(ws + off);
    short* hB = hA + (size_t)cs * HID;
    float* cS = (float*)(hB + (size_t)cs * HID);

    hipMemsetAsync(d_out, 0, (size_t)out_size * sizeof(float), stream);
    hipMemsetAsync(denom, 0, (size_t)N_NODES * H_HEADS * sizeof(float), stream);
    hipMemsetAsync(amax_key, 0, (size_t)N_NODES * H_HEADS * sizeof(unsigned), stream);

    feat2bf16<<<(N_NODES * D_FEAT + 255) / 256, 256, 0, stream>>>(features, feats_bf);
    convert_weights<<<4 * HID, 128, 0, stream>>>(W_ih, W_hh, b_ih, b_hh, Wb_ih, Wb_hh, bias);

    for (int e0 = 0; e0 < E_EDGES; e0 += cs) {
        int cnt = E_EDGES - e0 < cs ? E_EDGES - e0 : cs;
        dim3 g((cnt + 127) / 128, 4 * HID / 128);
        const int* mpc = mp + (size_t)e0 * L_SEQ;
        short* eft_c = eft + (size_t)e0 * HID;
        lstm_mfma<1><<<g, 256, 0, stream>>>(feats_bf, mpc, Wb_ih, Wb_hh, bias, hA, hA, cS, 0, cnt);
        lstm_mfma<0><<<g, 256, 0, stream>>>(feats_bf, mpc, Wb_ih, Wb_hh, bias, hA, hB, cS, 1, cnt);
        lstm_mfma<0><<<g, 256, 0, stream>>>(feats_bf, mpc, Wb_ih, Wb_hh, bias, hB, hA, cS, 2, cnt);
        lstm_mfma<0><<<g, 256, 0, stream>>>(feats_bf, mpc, Wb_ih, Wb_hh, bias, hA, eft_c, cS, 3, cnt);
    }

    attn_logits<<<E_EDGES / 4, 256, 0, stream>>>(features, mp, (const __hip_bfloat16*)eft,
                                                 attn1_w, attn2, dst, a_scr, amax_key);
    exp_denom<<<(E_EDGES * H_HEADS + 255) / 256, 256, 0, stream>>>(dst, a_scr, amax_key, denom);
    scatter_out<<<E_EDGES, 256, 0, stream>>>(dst, a_scr, denom, (const __hip_bfloat16*)eft, out);
}

// Round 4
// 1530.146 us; speedup vs baseline: 9.2221x; 1.1362x over previous
//
#include <hip/hip_runtime.h>
#include <hip/hip_bf16.h>
#include <stdint.h>

// N=20000 nodes, E=100000 edges, L=4 steps, D=64, H=8, HID=512, gates=2048.
#define N_NODES 20000
#define E_EDGES 100000
#define L_SEQ   4
#define D_FEAT  64
#define H_HEADS 8
#define HID     512

typedef __attribute__((ext_vector_type(8))) short short8;   // 8 bf16 = 4 VGPRs
typedef __attribute__((ext_vector_type(4))) float floatx4;  // MFMA C/D

// ---------- math helpers ----------
__device__ __forceinline__ float sigmoidf_(float x) { return 1.0f / (1.0f + __expf(-x)); }
__device__ __forceinline__ float tanhf_(float x) {
    x = fminf(15.f, fmaxf(-15.f, x));
    float e = __expf(2.f * x);
    return (e - 1.f) / (e + 1.f);
}
__device__ __forceinline__ unsigned fkey(float f) {
    unsigned u = __float_as_uint(f);
    return (u & 0x80000000u) ? ~u : (u | 0x80000000u);
}
__device__ __forceinline__ float fdecode(unsigned k) {
    if (k == 0u) return 0.0f;
    unsigned u = (k & 0x80000000u) ? (k ^ 0x80000000u) : ~k;
    return __uint_as_float(u);
}
__device__ __forceinline__ short f2bf(float x) {
    __hip_bfloat16 b = __float2bfloat16(x);
    return *(short*)&b;
}
__device__ __forceinline__ float bf2f(short x) {
    __hip_bfloat16 b = *(__hip_bfloat16*)&x;
    return __bfloat162float(b);
}

// async global->LDS, 16B per lane; lds base wave-uniform (lane i -> base + i*16)
__device__ __forceinline__ void gload16(const void* g, const void* l) {
    __builtin_amdgcn_global_load_lds(
        (const __attribute__((address_space(1))) unsigned int*)(uintptr_t)g,
        (__attribute__((address_space(3))) unsigned int*)(unsigned int)(uintptr_t)l,
        16, 0, 0);
}

// ---------- one-time conversions ----------
__global__ __launch_bounds__(256) void feat2bf16(const float* __restrict__ f, short* __restrict__ fb) {
    int i = blockIdx.x * 256 + threadIdx.x;
    if (i < N_NODES * D_FEAT) fb[i] = f2bf(f[i]);
}

// Permute W rows: permuted row rp -> hblock=rp>>7, half=(rp>>6)&1, gate=(rp>>4)&3, j=rp&15
// original row ro = gate*512 + hblock*32 + half*16 + j
__global__ __launch_bounds__(128) void convert_weights(
    const float* __restrict__ W_ih, const float* __restrict__ W_hh,
    const float* __restrict__ b_ih, const float* __restrict__ b_hh,
    short* __restrict__ Wb_ih, short* __restrict__ Wb_hh, float* __restrict__ bias)
{
    int rp = blockIdx.x;
    int hblock = rp >> 7, rem = rp & 127;
    int half = (rem >> 6) & 1, gate = (rem >> 4) & 3, j = rem & 15;
    int ro = gate * HID + hblock * 32 + half * 16 + j;
    for (int k = threadIdx.x; k < D_FEAT; k += 128)
        Wb_ih[rp * D_FEAT + k] = f2bf(W_ih[ro * D_FEAT + k]);
    for (int k = threadIdx.x; k < HID; k += 128)
        Wb_hh[rp * HID + k] = f2bf(W_hh[ro * HID + k]);
    if (threadIdx.x == 0) bias[ro] = b_ih[ro] + b_hh[ro];   // bias in ORIGINAL order
}

// ---------- MFMA LSTM step ----------
// 1D grid, XCD-swizzled: the 16 n-tiles (bn) of one 128-edge slice are 16 consecutive
// per-XCD slots -> the slice's A rows stay L2-resident on that XCD across all 16 bn.
// b = slot*8 + xcd (hw dispatch: b%8 -> XCD); slot = g*16 + bn; slice = g*8 + xcd.
template <int FIRST>
__global__ __launch_bounds__(256) void lstm_mfma(
    const short* __restrict__ feats_bf,   // N x 64 bf16
    const int*   __restrict__ mp,         // chunk: cnt x 4
    const short* __restrict__ Wb_ih,      // 2048 x 64 bf16 (permuted rows)
    const short* __restrict__ Wb_hh,      // 2048 x 512 bf16 (permuted rows)
    const float* __restrict__ bias,       // 2048 fp32 (original order)
    const short* __restrict__ h_prev,     // cnt x 512 bf16 (unused when FIRST)
    short*       __restrict__ h_next,     // cnt x 512 bf16
    short*       __restrict__ c_state,    // cnt x 512 bf16 (not read when FIRST)
    int t, int cnt, int nslices)
{
    __shared__ __align__(16) short At[128 * 64];
    __shared__ __align__(16) short Bt[128 * 64];

    const int b     = blockIdx.x;
    const int xcd   = b & 7;
    const int slot  = b >> 3;
    const int g     = slot >> 4;
    const int bn    = slot & 15;           // n-tile 0..15
    const int slice = g * 8 + xcd;
    if (slice >= nslices) return;          // block-uniform -> safe w.r.t. barriers
    const int e0    = slice * 128;
    const int hb    = bn * 32;

    const int tid   = threadIdx.x;
    const int lane  = tid & 63;
    const int w     = tid >> 6;
    const int waveM = w & 1;
    const int waveN = w >> 1;
    const int quad  = lane >> 4;
    const int c16   = lane & 15;

    floatx4 acc[4][4];
#pragma unroll
    for (int a = 0; a < 4; ++a)
#pragma unroll
        for (int bb = 0; bb < 4; ++bb) acc[a][bb] = (floatx4){0.f, 0.f, 0.f, 0.f};

    const int nch = FIRST ? 1 : 9;
    for (int kc = 0; kc < nch; ++kc) {
        // ---- stage A and B tiles (128 rows x 64 bf16 each) via global_load_lds ----
#pragma unroll
        for (int i = 0; i < 4; ++i) {
            int sb = w * 256 + i * 64;         // wave-uniform slot base
            int s  = sb + lane;
            int m  = s >> 3, p = s & 7;
            int pg = p ^ (m & 7);              // swizzled global kpart
            int e = e0 + m; if (e >= cnt) e = cnt - 1;
            const void* ga;
            if (kc == 0) {
                int row = mp[e * L_SEQ + t];
                ga = (const void*)(feats_bf + row * D_FEAT + pg * 8);
            } else {
                ga = (const void*)(h_prev + (size_t)e * HID + (kc - 1) * 64 + pg * 8);
            }
            gload16(ga, (const void*)&At[sb * 8]);
            int r = bn * 128 + m;
            const void* gb = (kc == 0)
                ? (const void*)(Wb_ih + r * D_FEAT + pg * 8)
                : (const void*)(Wb_hh + (size_t)r * HID + (kc - 1) * 64 + pg * 8);
            gload16(gb, (const void*)&Bt[sb * 8]);
        }
        __syncthreads();

#pragma unroll
        for (int ks = 0; ks < 2; ++ks) {
            short8 af[4], bfv[4];
#pragma unroll
            for (int mf = 0; mf < 4; ++mf) {
                int m  = waveM * 64 + mf * 16 + c16;
                int pw = ks * 4 + quad;
                af[mf] = *(const short8*)&At[m * 64 + ((pw ^ (m & 7)) * 8)];
            }
#pragma unroll
            for (int nf = 0; nf < 4; ++nf) {
                int n  = waveN * 64 + nf * 16 + c16;
                int pw = ks * 4 + quad;
                bfv[nf] = *(const short8*)&Bt[n * 64 + ((pw ^ (n & 7)) * 8)];
            }
#pragma unroll
            for (int mf = 0; mf < 4; ++mf)
#pragma unroll
                for (int nf = 0; nf < 4; ++nf)
                    acc[mf][nf] = __builtin_amdgcn_mfma_f32_16x16x32_bf16(
                        af[mf], bfv[nf], acc[mf][nf], 0, 0, 0);
        }
        __syncthreads();
    }

    // ---- epilogue: n-frag index IS the gate (0=i,1=f,2=g,3=o), all in-lane ----
    const int n = hb + waveN * 16 + c16;
    const float bi  = bias[n];
    const float bff = bias[HID + n];
    const float bg  = bias[2 * HID + n];
    const float bo  = bias[3 * HID + n];
#pragma unroll
    for (int mf = 0; mf < 4; ++mf) {
#pragma unroll
        for (int r = 0; r < 4; ++r) {
            int e = e0 + waveM * 64 + mf * 16 + quad * 4 + r;
            if (e < cnt) {
                float gi = acc[mf][0][r] + bi;
                float gf = acc[mf][1][r] + bff;
                float gg = acc[mf][2][r] + bg;
                float go = acc[mf][3][r] + bo;
                float c_old = FIRST ? 0.f : bf2f(c_state[(size_t)e * HID + n]);
                float cn = sigmoidf_(gf) * c_old + sigmoidf_(gi) * tanhf_(gg);
                c_state[(size_t)e * HID + n] = f2bf(cn);
                h_next[(size_t)e * HID + n] = f2bf(sigmoidf_(go) * tanhf_(cn));
            }
        }
    }
}

// ---------- attention logits + segment max (one 64-lane wave per edge) ----------
__global__ __launch_bounds__(256) void attn_logits(
    const float* __restrict__ features,
    const int*   __restrict__ mp,
    const __hip_bfloat16* __restrict__ hfin,   // E x 512 (E,H,D)
    const float* __restrict__ attn1_w,
    const float* __restrict__ attn2,
    const int*   __restrict__ dst,
    float*       __restrict__ a_out,           // E x H
    unsigned*    __restrict__ amax_key)        // N x H
{
    const int e    = blockIdx.x * 4 + (threadIdx.x >> 6);
    const int lane = threadIdx.x & 63;
    const int ctr  = mp[e * L_SEQ + (L_SEQ - 1)];
    const float cd = features[ctr * D_FEAT + lane];
    const int dn   = dst[e];
#pragma unroll
    for (int h = 0; h < H_HEADS; ++h) {
        float v = cd * attn1_w[h * D_FEAT + lane]
                + __bfloat162float(hfin[(size_t)e * HID + h * D_FEAT + lane]) * attn2[h * D_FEAT + lane];
#pragma unroll
        for (int off = 32; off; off >>= 1) v += __shfl_xor(v, off, 64);
        if (lane == 0) {
            float lv = v > 0.f ? v : 0.01f * v;
            a_out[e * H_HEADS + h] = lv;
            atomicMax(&amax_key[dn * H_HEADS + h], fkey(lv));
        }
    }
}

__global__ __launch_bounds__(256) void exp_denom(
    const int*      __restrict__ dst,
    float*          __restrict__ a_out,
    const unsigned* __restrict__ amax_key,
    float*          __restrict__ denom)
{
    int i = blockIdx.x * 256 + threadIdx.x;
    if (i >= E_EDGES * H_HEADS) return;
    int e = i >> 3, h = i & 7;
    int dn = dst[e];
    float am = fdecode(amax_key[dn * H_HEADS + h]);
    float ex = __expf(a_out[i] - am);
    a_out[i] = ex;
    atomicAdd(&denom[dn * H_HEADS + h], ex);
}

__global__ __launch_bounds__(256) void scatter_out(
    const int*   __restrict__ dst,
    const float* __restrict__ a_out,
    const float* __restrict__ denom,
    const __hip_bfloat16* __restrict__ hfin,
    float*       __restrict__ out)
{
    const int e  = blockIdx.x;
    const int dn = dst[e];
    for (int j = threadIdx.x; j < HID; j += 256) {
        int h = j >> 6;
        float wgt = a_out[e * H_HEADS + h] / denom[dn * H_HEADS + h];
        atomicAdd(&out[(size_t)dn * HID + j], __bfloat162float(hfin[(size_t)e * HID + j]) * wgt);
    }
}

extern "C" void kernel_launch(void* const* d_in, const int* in_sizes, int n_in,
                              void* d_out, int out_size, void* d_ws, size_t ws_size,
                              hipStream_t stream) {
    const float* features = (const float*)d_in[0];
    // d_in[1] = type_mask: unused
    const int*   mp       = (const int*)d_in[2];
    const int*   dst      = (const int*)d_in[3];
    const float* W_ih     = (const float*)d_in[4];
    const float* W_hh     = (const float*)d_in[5];
    const float* b_ih     = (const float*)d_in[6];
    const float* b_hh     = (const float*)d_in[7];
    const float* attn1_w  = (const float*)d_in[8];
    const float* attn2    = (const float*)d_in[9];
    float* out = (float*)d_out;

    // ---- workspace layout (deterministic given ws_size -> graph-safe) ----
    char* ws = (char*)d_ws;
    size_t off = 0;
    float*    a_scr    = (float*)(ws + off); off += (size_t)E_EDGES * H_HEADS * sizeof(float);
    float*    denom    = (float*)(ws + off); off += (size_t)N_NODES * H_HEADS * sizeof(float);
    unsigned* amax_key = (unsigned*)(ws + off); off += (size_t)N_NODES * H_HEADS * sizeof(unsigned);
    short*    feats_bf = (short*)(ws + off); off += (size_t)N_NODES * D_FEAT * sizeof(short);
    short*    Wb_ih    = (short*)(ws + off); off += (size_t)4 * HID * D_FEAT * sizeof(short);
    short*    Wb_hh    = (short*)(ws + off); off += (size_t)4 * HID * HID * sizeof(short);
    float*    bias     = (float*)(ws + off); off += (size_t)4 * HID * sizeof(float);
    off = (off + 255) & ~(size_t)255;
    short*    eft      = (short*)(ws + off); off += (size_t)E_EDGES * HID * sizeof(short);  // 102.4 MB
    off = (off + 255) & ~(size_t)255;

    // chunk buffers: hA(bf16) + hB(bf16) + c(bf16) = 3 KB/edge
    const size_t per_edge = (size_t)HID * (2 + 2 + 2);
    size_t avail = (ws_size > off) ? (ws_size - off) : 0;
    long long cs_ll = ((long long)(avail / per_edge) / 1024) * 1024;  // keep slices %8==0
    int cs = (int)(cs_ll < 1024 ? 1024 : (cs_ll > E_EDGES ? E_EDGES : cs_ll));

    short* hA = (short*)(ws + off);
    short* hB = hA + (size_t)cs * HID;
    short* cS = hB + (size_t)cs * HID;

    hipMemsetAsync(d_out, 0, (size_t)out_size * sizeof(float), stream);
    hipMemsetAsync(denom, 0, (size_t)N_NODES * H_HEADS * sizeof(float), stream);
    hipMemsetAsync(amax_key, 0, (size_t)N_NODES * H_HEADS * sizeof(unsigned), stream);

    feat2bf16<<<(N_NODES * D_FEAT + 255) / 256, 256, 0, stream>>>(features, feats_bf);
    convert_weights<<<4 * HID, 128, 0, stream>>>(W_ih, W_hh, b_ih, b_hh, Wb_ih, Wb_hh, bias);

    for (int e0 = 0; e0 < E_EDGES; e0 += cs) {
        int cnt = E_EDGES - e0 < cs ? E_EDGES - e0 : cs;
        int nslices = (cnt + 127) / 128;
        int nslices_pad = (nslices + 7) & ~7;
        int nblk = nslices_pad * 16;        // 1D grid, XCD-swizzled decode in-kernel
        const int* mpc = mp + (size_t)e0 * L_SEQ;
        short* eft_c = eft + (size_t)e0 * HID;
        lstm_mfma<1><<<nblk, 256, 0, stream>>>(feats_bf, mpc, Wb_ih, Wb_hh, bias, hA, hA, cS, 0, cnt, nslices);
        lstm_mfma<0><<<nblk, 256, 0, stream>>>(feats_bf, mpc, Wb_ih, Wb_hh, bias, hA, hB, cS, 1, cnt, nslices);
        lstm_mfma<0><<<nblk, 256, 0, stream>>>(feats_bf, mpc, Wb_ih, Wb_hh, bias, hB, hA, cS, 2, cnt, nslices);
        lstm_mfma<0><<<nblk, 256, 0, stream>>>(feats_bf, mpc, Wb_ih, Wb_hh, bias, hA, eft_c, cS, 3, cnt, nslices);
    }

    attn_logits<<<E_EDGES / 4, 256, 0, stream>>>(features, mp, (const __hip_bfloat16*)eft,
                                                 attn1_w, attn2, dst, a_scr, amax_key);
    exp_denom<<<(E_EDGES * H_HEADS + 255) / 256, 256, 0, stream>>>(dst, a_scr, amax_key, denom);
    scatter_out<<<E_EDGES, 256, 0, stream>>>(dst, a_scr, denom, (const __hip_bfloat16*)eft, out);
}

// Round 5
// 1476.194 us; speedup vs baseline: 9.5592x; 1.0365x over previous
//
#include <hip/hip_runtime.h>
#include <hip/hip_bf16.h>
#include <stdint.h>

// N=20000 nodes, E=100000 edges, L=4 steps, D=64, H=8, HID=512, gates=2048.
#define N_NODES 20000
#define E_EDGES 100000
#define L_SEQ   4
#define D_FEAT  64
#define H_HEADS 8
#define HID     512

typedef __attribute__((ext_vector_type(8))) short short8;   // 8 bf16 = 4 VGPRs
typedef __attribute__((ext_vector_type(4))) float floatx4;  // MFMA C/D

// ---------- math helpers ----------
__device__ __forceinline__ float sigmoidf_(float x) { return 1.0f / (1.0f + __expf(-x)); }
__device__ __forceinline__ float tanhf_(float x) {
    x = fminf(15.f, fmaxf(-15.f, x));
    float e = __expf(2.f * x);
    return (e - 1.f) / (e + 1.f);
}
__device__ __forceinline__ unsigned fkey(float f) {
    unsigned u = __float_as_uint(f);
    return (u & 0x80000000u) ? ~u : (u | 0x80000000u);
}
__device__ __forceinline__ float fdecode(unsigned k) {
    if (k == 0u) return 0.0f;
    unsigned u = (k & 0x80000000u) ? (k ^ 0x80000000u) : ~k;
    return __uint_as_float(u);
}
__device__ __forceinline__ short f2bf(float x) {
    __hip_bfloat16 b = __float2bfloat16(x);
    return *(short*)&b;
}
__device__ __forceinline__ float bf2f(short x) {
    __hip_bfloat16 b = *(__hip_bfloat16*)&x;
    return __bfloat162float(b);
}

// async global->LDS, 16B/lane; lds base wave-uniform (lane i -> base + i*16)
__device__ __forceinline__ void gload16(const void* g, const void* l) {
    __builtin_amdgcn_global_load_lds(
        (const __attribute__((address_space(1))) unsigned int*)(uintptr_t)g,
        (__attribute__((address_space(3))) unsigned int*)(unsigned int)(uintptr_t)l,
        16, 0, 0);
}

// ---------- one-time conversions ----------
__global__ __launch_bounds__(256) void feat2bf16(const float* __restrict__ f, short* __restrict__ fb) {
    int i = blockIdx.x * 256 + threadIdx.x;
    if (i < N_NODES * D_FEAT) fb[i] = f2bf(f[i]);
}

// Permute W rows: rp -> hblock=rp>>7, half=(rp>>6)&1, gate=(rp>>4)&3, j=rp&15
// original row ro = gate*512 + hblock*32 + half*16 + j
__global__ __launch_bounds__(128) void convert_weights(
    const float* __restrict__ W_ih, const float* __restrict__ W_hh,
    const float* __restrict__ b_ih, const float* __restrict__ b_hh,
    short* __restrict__ Wb_ih, short* __restrict__ Wb_hh, float* __restrict__ bias)
{
    int rp = blockIdx.x;
    int hblock = rp >> 7, rem = rp & 127;
    int half = (rem >> 6) & 1, gate = (rem >> 4) & 3, j = rem & 15;
    int ro = gate * HID + hblock * 32 + half * 16 + j;
    for (int k = threadIdx.x; k < D_FEAT; k += 128)
        Wb_ih[rp * D_FEAT + k] = f2bf(W_ih[ro * D_FEAT + k]);
    for (int k = threadIdx.x; k < HID; k += 128)
        Wb_hh[rp * HID + k] = f2bf(W_hh[ro * HID + k]);
    if (threadIdx.x == 0) bias[ro] = b_ih[ro] + b_hh[ro];   // bias in ORIGINAL order
}

// ---------- CSR build ----------
__global__ __launch_bounds__(256) void deg_hist(const int* __restrict__ dst, int* __restrict__ deg) {
    int i = blockIdx.x * 256 + threadIdx.x;
    if (i < E_EDGES) atomicAdd(&deg[dst[i]], 1);
}

// single-block exclusive scan of deg[0..N) -> row/cursor; row[N]=E
__global__ __launch_bounds__(1024) void scan_deg(const int* __restrict__ deg,
                                                 int* __restrict__ row, int* __restrict__ cursor) {
    __shared__ int buf[1024];
    __shared__ int s_carry;
    const int tid = threadIdx.x;
    if (tid == 0) s_carry = 0;
    __syncthreads();
    for (int base = 0; base < N_NODES; base += 1024) {
        int idx = base + tid;
        int v = (idx < N_NODES) ? deg[idx] : 0;
        buf[tid] = v;
        __syncthreads();
        for (int offd = 1; offd < 1024; offd <<= 1) {
            int tv = (tid >= offd) ? buf[tid - offd] : 0;
            __syncthreads();
            buf[tid] += tv;
            __syncthreads();
        }
        int c0 = s_carry;
        if (idx < N_NODES) { row[idx] = c0 + buf[tid] - v; cursor[idx] = c0 + buf[tid] - v; }
        __syncthreads();
        if (tid == 1023) s_carry = c0 + buf[1023];
        __syncthreads();
    }
    if (tid == 0) row[N_NODES] = s_carry;
}

__global__ __launch_bounds__(256) void fill_csr(const int* __restrict__ dst,
                                                int* __restrict__ cursor, int* __restrict__ elist) {
    int i = blockIdx.x * 256 + threadIdx.x;
    if (i < E_EDGES) {
        int p = atomicAdd(&cursor[dst[i]], 1);
        elist[p] = i;
    }
}

// ---------- MFMA LSTM step ----------
// 1D grid, XCD-swizzled: 16 n-tiles of one 128-edge slice land on consecutive
// per-XCD slots -> slice A rows stay L2-resident. Staging addresses are affine in
// kc: peel kc=0 (features/W_ih), then advance per-lane pointers by +64 shorts.
template <int FIRST>
__global__ __launch_bounds__(256) void lstm_mfma(
    const short* __restrict__ feats_bf,   // N x 64 bf16
    const int*   __restrict__ mp,         // chunk: cnt x 4
    const short* __restrict__ Wb_ih,      // 2048 x 64 bf16 (permuted rows)
    const short* __restrict__ Wb_hh,      // 2048 x 512 bf16 (permuted rows)
    const float* __restrict__ bias,       // 2048 fp32 (original order)
    const short* __restrict__ h_prev,     // cnt x 512 bf16 (unused when FIRST)
    short*       __restrict__ h_next,     // cnt x 512 bf16
    short*       __restrict__ c_state,    // cnt x 512 bf16 (not read when FIRST)
    int t, int cnt, int nslices)
{
    __shared__ __align__(16) short At[128 * 64];
    __shared__ __align__(16) short Bt[128 * 64];

    const int b     = blockIdx.x;
    const int xcd   = b & 7;
    const int slot  = b >> 3;
    const int g     = slot >> 4;
    const int bn    = slot & 15;
    const int slice = g * 8 + xcd;
    if (slice >= nslices) return;          // block-uniform
    const int e0    = slice * 128;
    const int hb    = bn * 32;

    const int tid   = threadIdx.x;
    const int lane  = tid & 63;
    const int w     = tid >> 6;
    const int waveM = w & 1;
    const int waveN = w >> 1;
    const int quad  = lane >> 4;
    const int c16   = lane & 15;

    floatx4 acc[4][4];
#pragma unroll
    for (int a = 0; a < 4; ++a)
#pragma unroll
        for (int bb = 0; bb < 4; ++bb) acc[a][bb] = (floatx4){0.f, 0.f, 0.f, 0.f};

    // per-lane staging descriptors (computed once)
    int eidx[4], mm[4], pgo[4];
#pragma unroll
    for (int i = 0; i < 4; ++i) {
        int s = w * 256 + i * 64 + lane;
        int m = s >> 3, p = s & 7;
        pgo[i] = p ^ (m & 7);
        mm[i]  = m;
        int e  = e0 + m; if (e >= cnt) e = cnt - 1;
        eidx[i] = e;
    }

    auto compute = [&]() {
#pragma unroll
        for (int ks = 0; ks < 2; ++ks) {
            short8 af[4], bfv[4];
#pragma unroll
            for (int mf = 0; mf < 4; ++mf) {
                int m  = waveM * 64 + mf * 16 + c16;
                int pw = ks * 4 + quad;
                af[mf] = *(const short8*)&At[m * 64 + ((pw ^ (m & 7)) * 8)];
            }
#pragma unroll
            for (int nf = 0; nf < 4; ++nf) {
                int n  = waveN * 64 + nf * 16 + c16;
                int pw = ks * 4 + quad;
                bfv[nf] = *(const short8*)&Bt[n * 64 + ((pw ^ (n & 7)) * 8)];
            }
#pragma unroll
            for (int mf = 0; mf < 4; ++mf)
#pragma unroll
                for (int nf = 0; nf < 4; ++nf)
                    acc[mf][nf] = __builtin_amdgcn_mfma_f32_16x16x32_bf16(
                        af[mf], bfv[nf], acc[mf][nf], 0, 0, 0);
        }
    };

    // ---- kc = 0: features + Wb_ih ----
#pragma unroll
    for (int i = 0; i < 4; ++i) {
        int sb = w * 256 + i * 64;
        int rowf = mp[eidx[i] * L_SEQ + t];
        gload16((const void*)(feats_bf + rowf * D_FEAT + pgo[i] * 8), (const void*)&At[sb * 8]);
        gload16((const void*)(Wb_ih + (bn * 128 + mm[i]) * D_FEAT + pgo[i] * 8), (const void*)&Bt[sb * 8]);
    }
    __syncthreads();
    compute();

    if (!FIRST) {
        // incremental pointers: +64 shorts (=128 B) per K-chunk
        const short* ah[4]; const short* bh[4];
#pragma unroll
        for (int i = 0; i < 4; ++i) {
            ah[i] = h_prev + (size_t)eidx[i] * HID + pgo[i] * 8;
            bh[i] = Wb_hh + (size_t)(bn * 128 + mm[i]) * HID + pgo[i] * 8;
        }
        for (int kc = 1; kc <= 8; ++kc) {
            __syncthreads();               // guard LDS overwrite vs prior compute
#pragma unroll
            for (int i = 0; i < 4; ++i) {
                int sb = w * 256 + i * 64;
                gload16((const void*)ah[i], (const void*)&At[sb * 8]);
                gload16((const void*)bh[i], (const void*)&Bt[sb * 8]);
                ah[i] += 64; bh[i] += 64;
            }
            __syncthreads();
            compute();
        }
    }

    // ---- epilogue: n-frag index IS the gate (0=i,1=f,2=g,3=o), all in-lane ----
    const int n = hb + waveN * 16 + c16;
    const float bi  = bias[n];
    const float bff = bias[HID + n];
    const float bg  = bias[2 * HID + n];
    const float bo  = bias[3 * HID + n];
#pragma unroll
    for (int mf = 0; mf < 4; ++mf) {
#pragma unroll
        for (int r = 0; r < 4; ++r) {
            int e = e0 + waveM * 64 + mf * 16 + quad * 4 + r;
            if (e < cnt) {
                float gi = acc[mf][0][r] + bi;
                float gf = acc[mf][1][r] + bff;
                float gg = acc[mf][2][r] + bg;
                float go = acc[mf][3][r] + bo;
                float c_old = FIRST ? 0.f : bf2f(c_state[(size_t)e * HID + n]);
                float cn = sigmoidf_(gf) * c_old + sigmoidf_(gi) * tanhf_(gg);
                c_state[(size_t)e * HID + n] = f2bf(cn);
                h_next[(size_t)e * HID + n] = f2bf(sigmoidf_(go) * tanhf_(cn));
            }
        }
    }
}

// ---------- attention logits (one 64-lane wave per edge; no atomics) ----------
__global__ __launch_bounds__(256) void attn_logits(
    const float* __restrict__ features,
    const int*   __restrict__ mp,
    const __hip_bfloat16* __restrict__ hfin,   // E x 512 (E,H,D)
    const float* __restrict__ attn1_w,
    const float* __restrict__ attn2,
    float*       __restrict__ a_out)           // E x H
{
    const int e    = blockIdx.x * 4 + (threadIdx.x >> 6);
    const int lane = threadIdx.x & 63;
    const int ctr  = mp[e * L_SEQ + (L_SEQ - 1)];
    const float cd = features[ctr * D_FEAT + lane];
#pragma unroll
    for (int h = 0; h < H_HEADS; ++h) {
        float v = cd * attn1_w[h * D_FEAT + lane]
                + __bfloat162float(hfin[(size_t)e * HID + h * D_FEAT + lane]) * attn2[h * D_FEAT + lane];
#pragma unroll
        for (int off = 32; off; off >>= 1) v += __shfl_xor(v, off, 64);
        if (lane == 0) {
            float lv = v > 0.f ? v : 0.01f * v;
            a_out[e * H_HEADS + h] = lv;
        }
    }
}

// ---------- per-node segment softmax + weighted gather (no global atomics) ----------
__global__ __launch_bounds__(256) void gather_out(
    const int*   __restrict__ row,
    const int*   __restrict__ elist,
    const float* __restrict__ a_scr,    // E x H logits
    const short* __restrict__ eft,      // E x 512 bf16
    float*       __restrict__ out)      // N x 512
{
    const int n   = blockIdx.x;
    const int tid = threadIdx.x;
    const int beg = row[n];
    const int deg = row[n + 1] - beg;
    const int j0 = tid, j1 = tid + 256;

    if (deg == 0) {
        out[(size_t)n * HID + j0] = 0.f;
        out[(size_t)n * HID + j1] = 0.f;
        return;
    }

    __shared__ unsigned s_maxu[H_HEADS];
    __shared__ float    s_max[H_HEADS];
    __shared__ float    s_den[H_HEADS];
    __shared__ float    s_w[128 * H_HEADS];
    __shared__ int      s_e[128];

    if (tid < H_HEADS) { s_maxu[tid] = 0u; s_den[tid] = 0.f; }
    __syncthreads();
    for (int i = tid; i < deg * H_HEADS; i += 256) {
        int e = elist[beg + (i >> 3)], h = i & 7;
        atomicMax(&s_maxu[h], fkey(a_scr[e * H_HEADS + h]));
    }
    __syncthreads();
    if (tid < H_HEADS) s_max[tid] = fdecode(s_maxu[tid]);
    __syncthreads();
    for (int i = tid; i < deg * H_HEADS; i += 256) {
        int e = elist[beg + (i >> 3)], h = i & 7;
        atomicAdd(&s_den[h], __expf(a_scr[e * H_HEADS + h] - s_max[h]));
    }
    __syncthreads();

    float acc0 = 0.f, acc1 = 0.f;
    const int h0 = j0 >> 6, h1 = j1 >> 6;
    for (int c0 = 0; c0 < deg; c0 += 128) {
        int cc = min(128, deg - c0);
        if (tid < cc) s_e[tid] = elist[beg + c0 + tid];
        __syncthreads();
        for (int i = tid; i < cc * H_HEADS; i += 256) {
            int k = i >> 3, h = i & 7;
            s_w[k * H_HEADS + h] = __expf(a_scr[s_e[k] * H_HEADS + h] - s_max[h]) / s_den[h];
        }
        __syncthreads();
        for (int k = 0; k < cc; ++k) {
            const short* er = eft + (size_t)s_e[k] * HID;
            acc0 += s_w[k * H_HEADS + h0] * bf2f(er[j0]);
            acc1 += s_w[k * H_HEADS + h1] * bf2f(er[j1]);
        }
        __syncthreads();
    }
    out[(size_t)n * HID + j0] = acc0;
    out[(size_t)n * HID + j1] = acc1;
}

extern "C" void kernel_launch(void* const* d_in, const int* in_sizes, int n_in,
                              void* d_out, int out_size, void* d_ws, size_t ws_size,
                              hipStream_t stream) {
    const float* features = (const float*)d_in[0];
    // d_in[1] = type_mask: unused
    const int*   mp       = (const int*)d_in[2];
    const int*   dst      = (const int*)d_in[3];
    const float* W_ih     = (const float*)d_in[4];
    const float* W_hh     = (const float*)d_in[5];
    const float* b_ih     = (const float*)d_in[6];
    const float* b_hh     = (const float*)d_in[7];
    const float* attn1_w  = (const float*)d_in[8];
    const float* attn2    = (const float*)d_in[9];
    float* out = (float*)d_out;

    // ---- workspace layout (deterministic given ws_size -> graph-safe) ----
    char* ws = (char*)d_ws;
    size_t off = 0;
    float* a_scr    = (float*)(ws + off); off += (size_t)E_EDGES * H_HEADS * sizeof(float);  // 3.2 MB
    int*   deg      = (int*)(ws + off);   off += (size_t)N_NODES * sizeof(int);
    int*   row      = (int*)(ws + off);   off += ((size_t)N_NODES + 1) * sizeof(int);
    int*   cursor   = (int*)(ws + off);   off += (size_t)N_NODES * sizeof(int);
    int*   elist    = (int*)(ws + off);   off += (size_t)E_EDGES * sizeof(int);
    short* feats_bf = (short*)(ws + off); off += (size_t)N_NODES * D_FEAT * sizeof(short);
    short* Wb_ih    = (short*)(ws + off); off += (size_t)4 * HID * D_FEAT * sizeof(short);
    short* Wb_hh    = (short*)(ws + off); off += (size_t)4 * HID * HID * sizeof(short);
    float* bias     = (float*)(ws + off); off += (size_t)4 * HID * sizeof(float);
    off = (off + 255) & ~(size_t)255;
    short* eft      = (short*)(ws + off); off += (size_t)E_EDGES * HID * sizeof(short);      // 102.4 MB
    off = (off + 255) & ~(size_t)255;

    // chunk buffers: hA + hB + c, all bf16 = 3 KB/edge
    const size_t per_edge = (size_t)HID * (2 + 2 + 2);
    size_t avail = (ws_size > off) ? (ws_size - off) : 0;
    long long cs_ll = ((long long)(avail / per_edge) / 1024) * 1024;
    int cs = (int)(cs_ll < 1024 ? 1024 : (cs_ll > E_EDGES ? E_EDGES : cs_ll));

    short* hA = (short*)(ws + off);
    short* hB = hA + (size_t)cs * HID;
    short* cS = hB + (size_t)cs * HID;

    // ---- CSR build (independent of LSTM chain) ----
    hipMemsetAsync(deg, 0, (size_t)N_NODES * sizeof(int), stream);
    deg_hist<<<(E_EDGES + 255) / 256, 256, 0, stream>>>(dst, deg);
    scan_deg<<<1, 1024, 0, stream>>>(deg, row, cursor);
    fill_csr<<<(E_EDGES + 255) / 256, 256, 0, stream>>>(dst, cursor, elist);

    // ---- conversions ----
    feat2bf16<<<(N_NODES * D_FEAT + 255) / 256, 256, 0, stream>>>(features, feats_bf);
    convert_weights<<<4 * HID, 128, 0, stream>>>(W_ih, W_hh, b_ih, b_hh, Wb_ih, Wb_hh, bias);

    // ---- LSTM chain (chunked over E) ----
    for (int e0 = 0; e0 < E_EDGES; e0 += cs) {
        int cnt = E_EDGES - e0 < cs ? E_EDGES - e0 : cs;
        int nslices = (cnt + 127) / 128;
        int nslices_pad = (nslices + 7) & ~7;
        int nblk = nslices_pad * 16;
        const int* mpc = mp + (size_t)e0 * L_SEQ;
        short* eft_c = eft + (size_t)e0 * HID;
        lstm_mfma<1><<<nblk, 256, 0, stream>>>(feats_bf, mpc, Wb_ih, Wb_hh, bias, hA, hA, cS, 0, cnt, nslices);
        lstm_mfma<0><<<nblk, 256, 0, stream>>>(feats_bf, mpc, Wb_ih, Wb_hh, bias, hA, hB, cS, 1, cnt, nslices);
        lstm_mfma<0><<<nblk, 256, 0, stream>>>(feats_bf, mpc, Wb_ih, Wb_hh, bias, hB, hA, cS, 2, cnt, nslices);
        lstm_mfma<0><<<nblk, 256, 0, stream>>>(feats_bf, mpc, Wb_ih, Wb_hh, bias, hA, eft_c, cS, 3, cnt, nslices);
    }

    // ---- attention: logits -> per-node softmax gather ----
    attn_logits<<<E_EDGES / 4, 256, 0, stream>>>(features, mp, (const __hip_bfloat16*)eft,
                                                 attn1_w, attn2, a_scr);
    gather_out<<<N_NODES, 256, 0, stream>>>(row, elist, a_scr, eft, out);
}

// Round 6
// 1344.768 us; speedup vs baseline: 10.4934x; 1.0977x over previous
//
#include <hip/hip_runtime.h>
#include <hip/hip_bf16.h>
#include <stdint.h>

// N=20000 nodes, E=100000 edges, L=4 steps, D=64, H=8, HID=512, gates=2048.
#define N_NODES 20000
#define E_EDGES 100000
#define L_SEQ   4
#define D_FEAT  64
#define H_HEADS 8
#define HID     512

typedef __attribute__((ext_vector_type(8))) short short8;   // 8 bf16 = 4 VGPRs
typedef __attribute__((ext_vector_type(4))) float floatx4;  // MFMA C/D

// ---------- math helpers ----------
__device__ __forceinline__ float sigmoidf_(float x) { return 1.0f / (1.0f + __expf(-x)); }
__device__ __forceinline__ float tanhf_(float x) {
    x = fminf(15.f, fmaxf(-15.f, x));
    float e = __expf(2.f * x);
    return (e - 1.f) / (e + 1.f);
}
__device__ __forceinline__ unsigned fkey(float f) {
    unsigned u = __float_as_uint(f);
    return (u & 0x80000000u) ? ~u : (u | 0x80000000u);
}
__device__ __forceinline__ float fdecode(unsigned k) {
    if (k == 0u) return 0.0f;
    unsigned u = (k & 0x80000000u) ? (k ^ 0x80000000u) : ~k;
    return __uint_as_float(u);
}
__device__ __forceinline__ short f2bf(float x) {
    __hip_bfloat16 b = __float2bfloat16(x);
    return *(short*)&b;
}
__device__ __forceinline__ float bf2f(short x) {
    __hip_bfloat16 b = *(__hip_bfloat16*)&x;
    return __bfloat162float(b);
}
// decode packed pair of bf16 from a uint
__device__ __forceinline__ float bfu_lo(unsigned v) { return __uint_as_float((v & 0xffffu) << 16); }
__device__ __forceinline__ float bfu_hi(unsigned v) { return __uint_as_float(v & 0xffff0000u); }

// async global->LDS, 16B/lane; lds base wave-uniform (lane i -> base + i*16)
__device__ __forceinline__ void gload16(const void* g, const void* l) {
    __builtin_amdgcn_global_load_lds(
        (const __attribute__((address_space(1))) unsigned int*)(uintptr_t)g,
        (__attribute__((address_space(3))) unsigned int*)(unsigned int)(uintptr_t)l,
        16, 0, 0);
}

// ---------- one-time conversions ----------
__global__ __launch_bounds__(256) void feat2bf16(const float* __restrict__ f, short* __restrict__ fb) {
    int i = blockIdx.x * 256 + threadIdx.x;
    if (i < N_NODES * D_FEAT) fb[i] = f2bf(f[i]);
}

// Permute W rows: rp -> hblock=rp>>7, half=(rp>>6)&1, gate=(rp>>4)&3, j=rp&15
// original row ro = gate*512 + hblock*32 + half*16 + j
__global__ __launch_bounds__(128) void convert_weights(
    const float* __restrict__ W_ih, const float* __restrict__ W_hh,
    const float* __restrict__ b_ih, const float* __restrict__ b_hh,
    short* __restrict__ Wb_ih, short* __restrict__ Wb_hh, float* __restrict__ bias)
{
    int rp = blockIdx.x;
    int hblock = rp >> 7, rem = rp & 127;
    int half = (rem >> 6) & 1, gate = (rem >> 4) & 3, j = rem & 15;
    int ro = gate * HID + hblock * 32 + half * 16 + j;
    for (int k = threadIdx.x; k < D_FEAT; k += 128)
        Wb_ih[rp * D_FEAT + k] = f2bf(W_ih[ro * D_FEAT + k]);
    for (int k = threadIdx.x; k < HID; k += 128)
        Wb_hh[rp * HID + k] = f2bf(W_hh[ro * HID + k]);
    if (threadIdx.x == 0) bias[ro] = b_ih[ro] + b_hh[ro];   // bias in ORIGINAL order
}

// ---------- CSR build ----------
__global__ __launch_bounds__(256) void deg_hist(const int* __restrict__ dst, int* __restrict__ deg) {
    int i = blockIdx.x * 256 + threadIdx.x;
    if (i < E_EDGES) atomicAdd(&deg[dst[i]], 1);
}

__global__ __launch_bounds__(1024) void scan_deg(const int* __restrict__ deg,
                                                 int* __restrict__ row, int* __restrict__ cursor) {
    __shared__ int buf[1024];
    __shared__ int s_carry;
    const int tid = threadIdx.x;
    if (tid == 0) s_carry = 0;
    __syncthreads();
    for (int base = 0; base < N_NODES; base += 1024) {
        int idx = base + tid;
        int v = (idx < N_NODES) ? deg[idx] : 0;
        buf[tid] = v;
        __syncthreads();
        for (int offd = 1; offd < 1024; offd <<= 1) {
            int tv = (tid >= offd) ? buf[tid - offd] : 0;
            __syncthreads();
            buf[tid] += tv;
            __syncthreads();
        }
        int c0 = s_carry;
        if (idx < N_NODES) { row[idx] = c0 + buf[tid] - v; cursor[idx] = c0 + buf[tid] - v; }
        __syncthreads();
        if (tid == 1023) s_carry = c0 + buf[1023];
        __syncthreads();
    }
    if (tid == 0) row[N_NODES] = s_carry;
}

__global__ __launch_bounds__(256) void fill_csr(const int* __restrict__ dst,
                                                int* __restrict__ cursor, int* __restrict__ elist) {
    int i = blockIdx.x * 256 + threadIdx.x;
    if (i < E_EDGES) {
        int p = atomicAdd(&cursor[dst[i]], 1);
        elist[p] = i;
    }
}

// ---------- MFMA LSTM step ----------
// MODE 0: node-init (t=0 folded to N-space): rows = node id, K=64, store h1,c1.
// MODE 1: step1: x=mp[e,1], h from h1[mp[e,0]] (node gather), c_old=c1[mp[e,0]], store h,c (chunk).
// MODE 2: mid step: h/c chunk-local, store h,c.
// MODE 3: last step: h/c chunk-local, store h only (c4 dead).
// 1D grid XCD-swizzled: 16 bn-tiles of one 128-row slice on consecutive per-XCD slots.
template <int MODE>
__global__ __launch_bounds__(256) void lstm_mfma(
    const short* __restrict__ feats_bf,   // N x 64 bf16
    const int*   __restrict__ mp,         // chunk-offset: cnt x 4 (unused MODE0)
    const short* __restrict__ Wb_ih,      // 2048 x 64 bf16 (permuted rows)
    const short* __restrict__ Wb_hh,      // 2048 x 512 bf16 (permuted rows)
    const float* __restrict__ bias,       // 2048 fp32 (original order)
    const short* __restrict__ h_src,      // MODE1: N x 512 (node); MODE2/3: cnt x 512
    const short* __restrict__ c_src,      // MODE1: N x 512 (node); MODE2/3: cnt x 512
    short*       __restrict__ h_dst,      // cnt x 512 (MODE0: N x 512)
    short*       __restrict__ c_dst,      // cnt x 512 (MODE0: N x 512; MODE3 unused)
    int t, int cnt, int nslices)
{
    __shared__ __align__(16) short At[128 * 64];
    __shared__ __align__(16) short Bt[128 * 64];

    const int b     = blockIdx.x;
    const int xcd   = b & 7;
    const int slot  = b >> 3;
    const int g     = slot >> 4;
    const int bn    = slot & 15;
    const int slice = g * 8 + xcd;
    if (slice >= nslices) return;          // block-uniform
    const int e0    = slice * 128;
    const int hb    = bn * 32;

    const int tid   = threadIdx.x;
    const int lane  = tid & 63;
    const int w     = tid >> 6;
    const int waveM = w & 1;
    const int waveN = w >> 1;
    const int quad  = lane >> 4;
    const int c16   = lane & 15;

    floatx4 acc[4][4];
#pragma unroll
    for (int a = 0; a < 4; ++a)
#pragma unroll
        for (int bb = 0; bb < 4; ++bb) acc[a][bb] = (floatx4){0.f, 0.f, 0.f, 0.f};

    // per-lane staging descriptors
    int eidx[4], mm[4], pgo[4], hrow[4];
#pragma unroll
    for (int i = 0; i < 4; ++i) {
        int s = w * 256 + i * 64 + lane;
        int m = s >> 3, p = s & 7;
        pgo[i] = p ^ (m & 7);
        mm[i]  = m;
        int e  = e0 + m; if (e >= cnt) e = cnt - 1;
        eidx[i] = e;
        if (MODE == 1) hrow[i] = mp[e * L_SEQ];   // node id supplying h1/c1
    }

    const int nch = (MODE == 0) ? 1 : 9;
    for (int kc = 0; kc < nch; ++kc) {
#pragma unroll
        for (int i = 0; i < 4; ++i) {
            int sb = w * 256 + i * 64;
            const void* ga;
            if (kc == 0) {
                int rowf = (MODE == 0) ? eidx[i] : mp[eidx[i] * L_SEQ + t];
                ga = (const void*)(feats_bf + rowf * D_FEAT + pgo[i] * 8);
            } else if (MODE == 1) {
                ga = (const void*)(h_src + (size_t)hrow[i] * HID + (kc - 1) * 64 + pgo[i] * 8);
            } else {
                ga = (const void*)(h_src + (size_t)eidx[i] * HID + (kc - 1) * 64 + pgo[i] * 8);
            }
            gload16(ga, (const void*)&At[sb * 8]);
            int r = bn * 128 + mm[i];
            const void* gb = (kc == 0)
                ? (const void*)(Wb_ih + r * D_FEAT + pgo[i] * 8)
                : (const void*)(Wb_hh + (size_t)r * HID + (kc - 1) * 64 + pgo[i] * 8);
            gload16(gb, (const void*)&Bt[sb * 8]);
        }
        __syncthreads();

#pragma unroll
        for (int ks = 0; ks < 2; ++ks) {
            short8 af[4], bfv[4];
#pragma unroll
            for (int mf = 0; mf < 4; ++mf) {
                int m  = waveM * 64 + mf * 16 + c16;
                int pw = ks * 4 + quad;
                af[mf] = *(const short8*)&At[m * 64 + ((pw ^ (m & 7)) * 8)];
            }
#pragma unroll
            for (int nf = 0; nf < 4; ++nf) {
                int n  = waveN * 64 + nf * 16 + c16;
                int pw = ks * 4 + quad;
                bfv[nf] = *(const short8*)&Bt[n * 64 + ((pw ^ (n & 7)) * 8)];
            }
#pragma unroll
            for (int mf = 0; mf < 4; ++mf)
#pragma unroll
                for (int nf = 0; nf < 4; ++nf)
                    acc[mf][nf] = __builtin_amdgcn_mfma_f32_16x16x32_bf16(
                        af[mf], bfv[nf], acc[mf][nf], 0, 0, 0);
        }
        __syncthreads();
    }

    // ---- epilogue: n-frag index IS the gate (0=i,1=f,2=g,3=o), all in-lane ----
    const int n = hb + waveN * 16 + c16;
    const float bi  = bias[n];
    const float bff = bias[HID + n];
    const float bg  = bias[2 * HID + n];
    const float bo  = bias[3 * HID + n];
#pragma unroll
    for (int mf = 0; mf < 4; ++mf) {
#pragma unroll
        for (int r = 0; r < 4; ++r) {
            int e = e0 + waveM * 64 + mf * 16 + quad * 4 + r;
            if (e < cnt) {
                float gi = acc[mf][0][r] + bi;
                float gf = acc[mf][1][r] + bff;
                float gg = acc[mf][2][r] + bg;
                float go = acc[mf][3][r] + bo;
                float c_old;
                if (MODE == 0)      c_old = 0.f;
                else if (MODE == 1) c_old = bf2f(c_src[(size_t)mp[e * L_SEQ] * HID + n]);
                else                c_old = bf2f(c_src[(size_t)e * HID + n]);
                float cn = sigmoidf_(gf) * c_old + sigmoidf_(gi) * tanhf_(gg);
                if (MODE != 3) c_dst[(size_t)e * HID + n] = f2bf(cn);
                h_dst[(size_t)e * HID + n] = f2bf(sigmoidf_(go) * tanhf_(cn));
            }
        }
    }
}

// ---------- attention logits (one wave per edge; vectorized, no atomics) ----------
__global__ __launch_bounds__(256) void attn_logits(
    const float* __restrict__ features,
    const int*   __restrict__ mp,
    const short* __restrict__ hfin,       // E x 512 bf16 (E,H,D)
    const float* __restrict__ attn1_w,    // H x 64
    const float* __restrict__ attn2,      // H x 64
    float*       __restrict__ a_out)      // E x H
{
    const int e    = blockIdx.x * 4 + (threadIdx.x >> 6);
    const int lane = threadIdx.x & 63;
    const int ctr  = mp[e * L_SEQ + (L_SEQ - 1)];
    // two passes: pass p covers heads p*4 .. p*4+3; lane -> (h = p*4 + lane>>4, d4 = (lane&15)*4)
#pragma unroll
    for (int p = 0; p < 2; ++p) {
        const int h  = p * 4 + (lane >> 4);
        const int d4 = (lane & 15) * 4;
        const float4 cd = *(const float4*)&features[ctr * D_FEAT + d4];
        const float4 a1 = *(const float4*)&attn1_w[h * D_FEAT + d4];
        const float4 a2 = *(const float4*)&attn2[h * D_FEAT + d4];
        const uint2 ev = *(const uint2*)&hfin[(size_t)e * HID + h * D_FEAT + d4];
        float v = cd.x * a1.x + cd.y * a1.y + cd.z * a1.z + cd.w * a1.w
                + bfu_lo(ev.x) * a2.x + bfu_hi(ev.x) * a2.y
                + bfu_lo(ev.y) * a2.z + bfu_hi(ev.y) * a2.w;
#pragma unroll
        for (int off = 1; off < 16; off <<= 1) v += __shfl_xor(v, off, 64);
        if ((lane & 15) == 0) {
            float lv = v > 0.f ? v : 0.01f * v;
            a_out[e * H_HEADS + h] = lv;
        }
    }
}

// ---------- per-node segment softmax + weighted gather (no global atomics) ----------
// thread tid owns dims j=2*tid, 2*tid+1 (one head: h = tid>>5); packed bf16 loads.
__global__ __launch_bounds__(256) void gather_out(
    const int*   __restrict__ row,
    const int*   __restrict__ elist,
    const float* __restrict__ a_scr,    // E x H logits
    const short* __restrict__ eft,      // E x 512 bf16
    float*       __restrict__ out)      // N x 512
{
    const int n   = blockIdx.x;
    const int tid = threadIdx.x;
    const int beg = row[n];
    const int deg = row[n + 1] - beg;
    const int j   = tid * 2;
    const int h   = tid >> 5;

    if (deg == 0) {
        *(float2*)&out[(size_t)n * HID + j] = (float2){0.f, 0.f};
        return;
    }

    __shared__ unsigned s_maxu[H_HEADS];
    __shared__ float    s_max[H_HEADS];
    __shared__ float    s_den[H_HEADS];
    __shared__ float    s_w[128 * H_HEADS];
    __shared__ int      s_e[128];

    if (tid < H_HEADS) { s_maxu[tid] = 0u; s_den[tid] = 0.f; }
    __syncthreads();
    for (int i = tid; i < deg * H_HEADS; i += 256) {
        int e = elist[beg + (i >> 3)], hh = i & 7;
        atomicMax(&s_maxu[hh], fkey(a_scr[e * H_HEADS + hh]));
    }
    __syncthreads();
    if (tid < H_HEADS) s_max[tid] = fdecode(s_maxu[tid]);
    __syncthreads();
    for (int i = tid; i < deg * H_HEADS; i += 256) {
        int e = elist[beg + (i >> 3)], hh = i & 7;
        atomicAdd(&s_den[hh], __expf(a_scr[e * H_HEADS + hh] - s_max[hh]));
    }
    __syncthreads();

    float acc0 = 0.f, acc1 = 0.f;
    for (int c0 = 0; c0 < deg; c0 += 128) {
        int cc = min(128, deg - c0);
        if (tid < cc) s_e[tid] = elist[beg + c0 + tid];
        __syncthreads();
        for (int i = tid; i < cc * H_HEADS; i += 256) {
            int k = i >> 3, hh = i & 7;
            s_w[k * H_HEADS + hh] = __expf(a_scr[s_e[k] * H_HEADS + hh] - s_max[hh]) / s_den[hh];
        }
        __syncthreads();
        for (int k = 0; k < cc; ++k) {
            unsigned v = *(const unsigned*)&eft[(size_t)s_e[k] * HID + j];
            float wgt = s_w[k * H_HEADS + h];
            acc0 += wgt * bfu_lo(v);
            acc1 += wgt * bfu_hi(v);
        }
        __syncthreads();
    }
    *(float2*)&out[(size_t)n * HID + j] = (float2){acc0, acc1};
}

extern "C" void kernel_launch(void* const* d_in, const int* in_sizes, int n_in,
                              void* d_out, int out_size, void* d_ws, size_t ws_size,
                              hipStream_t stream) {
    const float* features = (const float*)d_in[0];
    // d_in[1] = type_mask: unused
    const int*   mp       = (const int*)d_in[2];
    const int*   dst      = (const int*)d_in[3];
    const float* W_ih     = (const float*)d_in[4];
    const float* W_hh     = (const float*)d_in[5];
    const float* b_ih     = (const float*)d_in[6];
    const float* b_hh     = (const float*)d_in[7];
    const float* attn1_w  = (const float*)d_in[8];
    const float* attn2    = (const float*)d_in[9];
    float* out = (float*)d_out;

    // ---- workspace layout (deterministic given ws_size -> graph-safe) ----
    char* ws = (char*)d_ws;
    size_t off = 0;
    float* a_scr    = (float*)(ws + off); off += (size_t)E_EDGES * H_HEADS * sizeof(float);  // 3.2 MB
    int*   deg      = (int*)(ws + off);   off += (size_t)N_NODES * sizeof(int);
    int*   row      = (int*)(ws + off);   off += ((size_t)N_NODES + 1) * sizeof(int);
    int*   cursor   = (int*)(ws + off);   off += (size_t)N_NODES * sizeof(int);
    int*   elist    = (int*)(ws + off);   off += (size_t)E_EDGES * sizeof(int);
    short* feats_bf = (short*)(ws + off); off += (size_t)N_NODES * D_FEAT * sizeof(short);
    short* Wb_ih    = (short*)(ws + off); off += (size_t)4 * HID * D_FEAT * sizeof(short);
    short* Wb_hh    = (short*)(ws + off); off += (size_t)4 * HID * HID * sizeof(short);
    float* bias     = (float*)(ws + off); off += (size_t)4 * HID * sizeof(float);
    off = (off + 255) & ~(size_t)255;
    short* h1n      = (short*)(ws + off); off += (size_t)N_NODES * HID * sizeof(short);      // 20.5 MB
    short* c1n      = (short*)(ws + off); off += (size_t)N_NODES * HID * sizeof(short);      // 20.5 MB
    off = (off + 255) & ~(size_t)255;
    short* eft      = (short*)(ws + off); off += (size_t)E_EDGES * HID * sizeof(short);      // 102.4 MB
    off = (off + 255) & ~(size_t)255;

    // chunk buffers: hA + hB + cS, all bf16 = 3 KB/edge
    const size_t per_edge = (size_t)HID * (2 + 2 + 2);
    size_t avail = (ws_size > off) ? (ws_size - off) : 0;
    long long cs_ll = ((long long)(avail / per_edge) / 1024) * 1024;
    int cs = (int)(cs_ll < 1024 ? 1024 : (cs_ll > E_EDGES ? E_EDGES : cs_ll));

    short* hA = (short*)(ws + off);
    short* hB = hA + (size_t)cs * HID;
    short* cS = hB + (size_t)cs * HID;

    // ---- CSR build (independent of LSTM chain) ----
    hipMemsetAsync(deg, 0, (size_t)N_NODES * sizeof(int), stream);
    deg_hist<<<(E_EDGES + 255) / 256, 256, 0, stream>>>(dst, deg);
    scan_deg<<<1, 1024, 0, stream>>>(deg, row, cursor);
    fill_csr<<<(E_EDGES + 255) / 256, 256, 0, stream>>>(dst, cursor, elist);

    // ---- conversions ----
    feat2bf16<<<(N_NODES * D_FEAT + 255) / 256, 256, 0, stream>>>(features, feats_bf);
    convert_weights<<<4 * HID, 128, 0, stream>>>(W_ih, W_hh, b_ih, b_hh, Wb_ih, Wb_hh, bias);

    // ---- step 0 folded to node space: h1,c1 for all N nodes ----
    {
        int nslices = (N_NODES + 127) / 128;
        int nblk = ((nslices + 7) & ~7) * 16;
        lstm_mfma<0><<<nblk, 256, 0, stream>>>(feats_bf, nullptr, Wb_ih, Wb_hh, bias,
                                               nullptr, nullptr, h1n, c1n, 0, N_NODES, nslices);
    }

    // ---- steps 1..3 (chunked over E) ----
    for (int e0 = 0; e0 < E_EDGES; e0 += cs) {
        int cnt = E_EDGES - e0 < cs ? E_EDGES - e0 : cs;
        int nslices = (cnt + 127) / 128;
        int nblk = ((nslices + 7) & ~7) * 16;
        const int* mpc = mp + (size_t)e0 * L_SEQ;
        short* eft_c = eft + (size_t)e0 * HID;
        lstm_mfma<1><<<nblk, 256, 0, stream>>>(feats_bf, mpc, Wb_ih, Wb_hh, bias, h1n, c1n, hA, cS, 1, cnt, nslices);
        lstm_mfma<2><<<nblk, 256, 0, stream>>>(feats_bf, mpc, Wb_ih, Wb_hh, bias, hA, cS, hB, cS, 2, cnt, nslices);
        lstm_mfma<3><<<nblk, 256, 0, stream>>>(feats_bf, mpc, Wb_ih, Wb_hh, bias, hB, cS, eft_c, nullptr, 3, cnt, nslices);
    }

    // ---- attention: logits -> per-node softmax gather ----
    attn_logits<<<E_EDGES / 4, 256, 0, stream>>>(features, mp, eft, attn1_w, attn2, a_scr);
    gather_out<<<N_NODES, 256, 0, stream>>>(row, elist, a_scr, eft, out);
}